// Round 16
// baseline (62.851 us; speedup 1.0000x reference)
//
#include <hip/hip_runtime.h>
#include <hip/hip_bf16.h>

// AttentionLayer: B=8, T=12, N=512, D=256, H=8, head_dim=32, fp32 in/out.
// R16: 8-waves/SIMD at the <=64-reg quantum (m69: waves/SIMD steps at
// 64/128/256 regs — 5..7 waves/SIMD don't exist; R3/R8's cap-85 could never
// pay). 768 blocks (one per bt,h) x 1024 threads (16 waves); each wave owns
// 2 q-tiles (32 rows) -> block covers all 512 q-rows, K/V staged ONCE (no
// R11-style duplication). UN-batched QK per tile keeps s-regs at 8; total
// live ~58 <= 64. launch_bounds(1024,8) -> 2 blocks/CU = 32 waves/CU.
// Single 512-kv stage (64 KB LDS: K swizzled + V transposed/permuted-k,
// 2-way-max write conflicts). Swapped QK^T: s = mfma(K,Q,-12) -> P lane-local,
// exp2 feeds PV A-operand directly. Static-max softmax, truncation pack,
// scalar row-sum + 2-shuffle epilogue.
// Ledger: cap85 spills@4waves (R3,R8); cap128 clean 53.4us (R12); unroll-8
// spills (R9); q-split x4 staging-dominated (R11); setprio hurts (R14);
// kb-prefetch neutral (R15).

#define N_    512
#define DM    256
#define DH    32
#define CHUNK 512

typedef __attribute__((ext_vector_type(8))) short bf16x8;
typedef __attribute__((ext_vector_type(4))) float f32x4;

#if defined(__has_builtin)
#  if __has_builtin(__builtin_amdgcn_exp2f)
#    define FEXP2(x) __builtin_amdgcn_exp2f(x)
#  endif
#endif
#ifndef FEXP2
#  define FEXP2(x) exp2f(x)
#endif

__device__ __forceinline__ unsigned short f2bf(float f) {
    unsigned int u = __builtin_bit_cast(unsigned int, f);
    return (unsigned short)((u + 0x8000u) >> 16);   // round-half-up
}

__device__ __forceinline__ unsigned int pack_bf16_trunc(float a, float b) {
    // lo16 = trunc-bf16(a), hi16 = trunc-bf16(b): 2 VALU ops (lshr + and_or)
    const unsigned int ua = __builtin_bit_cast(unsigned int, a);
    const unsigned int ub = __builtin_bit_cast(unsigned int, b);
    return (ua >> 16) | (ub & 0xffff0000u);
}

__device__ __forceinline__ int fxor(int d) {
    // V granule swizzle: varies with d>>2 (per-lane) and d&3 (per-unroll-step)
    return ((d >> 2) ^ ((d & 3) << 1)) & 7;
}

__global__ __launch_bounds__(1024, 8) void attn_mha_kernel(
    const float* __restrict__ Q, const float* __restrict__ K,
    const float* __restrict__ V, float* __restrict__ O)
{
    // 32 KB (K) + 32 KB (V, permuted) = 65536 B LDS; 2 blocks/CU (wave-limited)
    __shared__ unsigned short kls[CHUNK * DH];   // K[kvl][d], granule slot = (d4>>1)^((kvl>>1)&3)
    __shared__ unsigned short vtls[DH * CHUNK];  // VT[d][perm(kvl)], granule ^= fxor(d)

    const int tid = threadIdx.x;
    const int bt = blockIdx.x >> 3;
    const int h  = blockIdx.x & 7;
    const size_t base = (size_t)bt * (N_ * DM) + (size_t)h * DH;
    const float* Qg = Q + base;
    const float* Kg = K + base;
    const float* Vg = V + base;
    float*       Og = O + base;

    const int wave = tid >> 6;   // 0..15
    const int lane = tid & 63;
    const int lr = lane & 15;   // q col for QK; A-row q / B-col d for PV
    const int lh = lane >> 4;   // depth group 0..3

    const float QSC = 0.25500826170f;             // log2(e)/sqrt(32)
    const int kslot = (lh ^ ((lr >> 1) & 3)) * 8; // K-frag swizzled granule (u16 units)

    // ---------------- Q fragments: 2 tiles of 16 rows per wave ----------------
    bf16x8 qf[2];
    #pragma unroll
    for (int t = 0; t < 2; ++t) {
        const int q0 = wave * 32 + t * 16;
        const float* qp = Qg + (size_t)(q0 + lr) * DM + lh * 8;
        const float4 qa = *(const float4*)qp;
        const float4 qb = *(const float4*)(qp + 4);
        bf16x8 q;
        q[0] = (short)f2bf(qa.x * QSC); q[1] = (short)f2bf(qa.y * QSC);
        q[2] = (short)f2bf(qa.z * QSC); q[3] = (short)f2bf(qa.w * QSC);
        q[4] = (short)f2bf(qb.x * QSC); q[5] = (short)f2bf(qb.y * QSC);
        q[6] = (short)f2bf(qb.z * QSC); q[7] = (short)f2bf(qb.w * QSC);
        qf[t] = q;
    }

    // ---------------- stage K (bf16), all 512 kv; 1024 threads ----------------
    {
        const int d4 = tid & 7;    // d = 4*d4
        const int r0 = tid >> 3;   // 0..127
        #pragma unroll 2
        for (int p = 0; p < 4; ++p) {
            const int kvl = p * 128 + r0;         // 0..511
            const float4 kf = *(const float4*)(Kg + (size_t)kvl * DM + d4 * 4);
            const int slot = (d4 >> 1) ^ ((kvl >> 1) & 3);
            ushort4 w;
            w.x = f2bf(kf.x); w.y = f2bf(kf.y); w.z = f2bf(kf.z); w.w = f2bf(kf.w);
            *(ushort4*)(&kls[kvl * 32 + slot * 8 + (d4 & 1) * 4]) = w;
        }
        // ---- stage V transposed + permuted-k order (bf16 pairs) ----
        // perm within each 32-group: pp = ((kvl>>2)&3)*8 + ((kvl>>4)&1)*4 + (kvl&3)
        // kvl bit-interleave: w&1 -> bit4, so granule-offset bytes spread 4 ways
        #pragma unroll 2
        for (int p = 0; p < 2; ++p) {
            const int m = p * 128 + r0;           // pair index 0..255
            const int grp = m >> 4;
            const int w   = m & 15;
            const int kvl = grp * 32 + ((w & 1) << 4) + ((w >> 1) << 1);  // even
            const float* vp = Vg + (size_t)kvl * DM + d4 * 4;
            const float4 a = *(const float4*)vp;
            const float4 b = *(const float4*)(vp + DM);
            const float av[4] = {a.x, a.y, a.z, a.w};
            const float bv[4] = {b.x, b.y, b.z, b.w};
            const int pp  = ((kvl >> 2) & 3) * 8 + ((kvl >> 4) & 1) * 4 + (kvl & 3);
            const int idx = (kvl & ~31) + pp;     // permuted index in row, even
            const int g  = idx >> 3;
            const int go = idx & 7;
            #pragma unroll
            for (int i = 0; i < 4; ++i) {
                const int d = d4 * 4 + i;
                const unsigned int pk =
                    (unsigned int)f2bf(av[i]) | ((unsigned int)f2bf(bv[i]) << 16);
                *(unsigned int*)(&vtls[d * CHUNK + (g ^ fxor(d)) * 8 + go]) = pk;
            }
        }
    }
    __syncthreads();

    f32x4 o0[2], o1[2];
    float ls[2];
    #pragma unroll
    for (int t = 0; t < 2; ++t) {
        o0[t] = (f32x4){0.f, 0.f, 0.f, 0.f};
        o1[t] = (f32x4){0.f, 0.f, 0.f, 0.f};
        ls[t] = 0.f;
    }

    // s = (q.k)*log2(e)/sqrt(d) - 12 directly via MFMA C-init.
    const f32x4 minit = {-12.f, -12.f, -12.f, -12.f};

    #pragma unroll 1
    for (int it = 0; it < 16; ++it) {
        const int c0 = it * 32;   // kv base

        // K A-fragments (rows k, depth d); V B-fragments (permuted, single b128)
        const bf16x8 kb0 = *(const bf16x8*)(&kls[(c0 + lr) * 32 + kslot]);
        const bf16x8 kb1 = *(const bf16x8*)(&kls[(c0 + 16 + lr) * 32 + kslot]);
        const int G = it * 4 + lh;
        const bf16x8 vb0 = *(const bf16x8*)(&vtls[lr * CHUNK + (G ^ fxor(lr)) * 8]);
        const bf16x8 vb1 = *(const bf16x8*)(&vtls[(16 + lr) * CHUNK + (G ^ fxor(16 + lr)) * 8]);

        // per q-tile, UN-batched (keeps s-register footprint at 8)
        #pragma unroll
        for (int t = 0; t < 2; ++t) {
            f32x4 s0 = __builtin_amdgcn_mfma_f32_16x16x32_bf16(kb0, qf[t], minit, 0, 0, 0);
            f32x4 s1 = __builtin_amdgcn_mfma_f32_16x16x32_bf16(kb1, qf[t], minit, 0, 0, 0);

            float p0[4], p1[4];
            #pragma unroll
            for (int r = 0; r < 4; ++r) {
                p0[r] = FEXP2(s0[r]);
                p1[r] = FEXP2(s1[r]);
            }
            ls[t] += (p0[0] + p0[1] + p0[2] + p0[3]) +
                     (p1[0] + p1[1] + p1[2] + p1[3]);

            union { unsigned int w[4]; bf16x8 v; } pa;
            pa.w[0] = pack_bf16_trunc(p0[0], p0[1]);
            pa.w[1] = pack_bf16_trunc(p0[2], p0[3]);
            pa.w[2] = pack_bf16_trunc(p1[0], p1[1]);
            pa.w[3] = pack_bf16_trunc(p1[2], p1[3]);

            o0[t] = __builtin_amdgcn_mfma_f32_16x16x32_bf16(pa.v, vb0, o0[t], 0, 0, 0);
            o1[t] = __builtin_amdgcn_mfma_f32_16x16x32_bf16(pa.v, vb1, o1[t], 0, 0, 0);
        }
    }

    // ------- epilogue: reduce row-sums (q = lr lane-local), normalize, store ----
    #pragma unroll
    for (int t = 0; t < 2; ++t) {
        float s = ls[t];
        s += __shfl_xor(s, 16);
        s += __shfl_xor(s, 32);   // all lanes now hold total for q = lr
        #pragma unroll
        for (int r = 0; r < 4; ++r) {
            const float inv = 1.0f / __shfl(s, lh * 4 + r);
            float* orow = Og + (size_t)(wave * 32 + t * 16 + lh * 4 + r) * DM;
            orow[lr]      = o0[t][r] * inv;
            orow[16 + lr] = o1[t][r] * inv;
        }
    }
}

extern "C" void kernel_launch(void* const* d_in, const int* in_sizes, int n_in,
                              void* d_out, int out_size, void* d_ws, size_t ws_size,
                              hipStream_t stream) {
    const float* Q = (const float*)d_in[0];
    const float* K = (const float*)d_in[1];
    const float* V = (const float*)d_in[2];
    float* O = (float*)d_out;
    attn_mha_kernel<<<dim3(96 * 8), dim3(1024), 0, stream>>>(Q, K, V, O);
}

// Round 17
// 53.502 us; speedup vs baseline: 1.1747x; 1.1747x over previous
//
#include <hip/hip_runtime.h>
#include <hip/hip_bf16.h>

// AttentionLayer: B=8, T=12, N=512, D=256, H=8, head_dim=32, fp32 in/out.
// 768 blocks (one per bt,h) x 512 threads (8 waves), launch_bounds (512,4).
// Single 512-kv stage (64 KB LDS; 2 blocks/CU). Swapped QK^T: s = mfma(K,Q,-12)
// -> P lane-local, exp2 feeds PV A-operand directly. Static-max softmax,
// truncation pack, scalar row-sum + 2-shuffle epilogue. (= R12 structure)
// R17: WAVE PHASE STAGGER — wave w iterates kv tiles starting at (w*2)&15,
// wrapping. Decorrelates the 8 waves' QK-MFMA / exp2-trans / LDS-read phases
// so shared pipes aren't transiently oversubscribed in lockstep. Sum over all
// 16 tiles is order-invariant -> identical math (fp-assoc only).
// Evidence: occupancy 70% didn't help (R16), 56% didn't (R11), setprio hurt
// on lockstep waves (R14), micro-scheduling neutral (R15) -> phase collision,
// not latency, is the stall mechanism.
// Ledger: cap85 spills (R3,R8); cap128 clean 53.4us (R12); unroll-8 spills
// (R9); q-split staging-dominated (R11); setprio hurts (R14); kb-prefetch
// neutral (R15); 8-wave/64-reg occupancy no-win (R16).

#define N_    512
#define DM    256
#define DH    32
#define CHUNK 512

typedef __attribute__((ext_vector_type(8))) short bf16x8;
typedef __attribute__((ext_vector_type(4))) float f32x4;

#if defined(__has_builtin)
#  if __has_builtin(__builtin_amdgcn_exp2f)
#    define FEXP2(x) __builtin_amdgcn_exp2f(x)
#  endif
#endif
#ifndef FEXP2
#  define FEXP2(x) exp2f(x)
#endif

__device__ __forceinline__ unsigned short f2bf(float f) {
    unsigned int u = __builtin_bit_cast(unsigned int, f);
    return (unsigned short)((u + 0x8000u) >> 16);   // round-half-up
}

__device__ __forceinline__ unsigned int pack_bf16_trunc(float a, float b) {
    // lo16 = trunc-bf16(a), hi16 = trunc-bf16(b): 2 VALU ops (lshr + and_or)
    const unsigned int ua = __builtin_bit_cast(unsigned int, a);
    const unsigned int ub = __builtin_bit_cast(unsigned int, b);
    return (ua >> 16) | (ub & 0xffff0000u);
}

__device__ __forceinline__ int fxor(int d) {
    // V granule swizzle: varies with d>>2 (per-lane) and d&3 (per-unroll-step)
    return ((d >> 2) ^ ((d & 3) << 1)) & 7;
}

__global__ __launch_bounds__(512, 4) void attn_mha_kernel(
    const float* __restrict__ Q, const float* __restrict__ K,
    const float* __restrict__ V, float* __restrict__ O)
{
    // 32 KB (K) + 32 KB (V, permuted) = 65536 B LDS; 2 blocks/CU (wave-limited)
    __shared__ unsigned short kls[CHUNK * DH];   // K[kvl][d], granule slot = (d4>>1)^((kvl>>1)&3)
    __shared__ unsigned short vtls[DH * CHUNK];  // VT[d][perm(kvl)], granule ^= fxor(d)

    const int tid = threadIdx.x;
    const int bt = blockIdx.x >> 3;
    const int h  = blockIdx.x & 7;
    const size_t base = (size_t)bt * (N_ * DM) + (size_t)h * DH;
    const float* Qg = Q + base;
    const float* Kg = K + base;
    const float* Vg = V + base;
    float*       Og = O + base;

    const int wave = tid >> 6;
    const int lane = tid & 63;
    const int lr = lane & 15;   // q col for QK; A-row q / B-col d for PV
    const int lh = lane >> 4;   // depth group 0..3

    const float QSC = 0.25500826170f;             // log2(e)/sqrt(32)
    const int kslot = (lh ^ ((lr >> 1) & 3)) * 8; // K-frag swizzled granule (u16 units)

    // ---------------- Q fragments: 4 tiles of 16 rows per wave ----------------
    bf16x8 qf[4];
    #pragma unroll
    for (int t = 0; t < 4; ++t) {
        const int q0 = wave * 64 + t * 16;
        const float* qp = Qg + (size_t)(q0 + lr) * DM + lh * 8;
        const float4 qa = *(const float4*)qp;
        const float4 qb = *(const float4*)(qp + 4);
        bf16x8 q;
        q[0] = (short)f2bf(qa.x * QSC); q[1] = (short)f2bf(qa.y * QSC);
        q[2] = (short)f2bf(qa.z * QSC); q[3] = (short)f2bf(qa.w * QSC);
        q[4] = (short)f2bf(qb.x * QSC); q[5] = (short)f2bf(qb.y * QSC);
        q[6] = (short)f2bf(qb.z * QSC); q[7] = (short)f2bf(qb.w * QSC);
        qf[t] = q;
    }

    f32x4 o0[4], o1[4];
    float ls[4];
    #pragma unroll
    for (int t = 0; t < 4; ++t) {
        o0[t] = (f32x4){0.f, 0.f, 0.f, 0.f};
        o1[t] = (f32x4){0.f, 0.f, 0.f, 0.f};
        ls[t] = 0.f;
    }

    // s = (q.k)*log2(e)/sqrt(d) - 12 directly via MFMA C-init.
    const f32x4 minit = {-12.f, -12.f, -12.f, -12.f};

    // ---------------- stage K (bf16), all 512 kv ----------------
    {
        const int d4 = tid & 7;    // d = 4*d4
        const int r0 = tid >> 3;   // 0..63
        #pragma unroll 2
        for (int p = 0; p < 8; ++p) {
            const int kvl = p * 64 + r0;          // 0..511
            const float4 kf = *(const float4*)(Kg + (size_t)kvl * DM + d4 * 4);
            const int slot = (d4 >> 1) ^ ((kvl >> 1) & 3);
            ushort4 w;
            w.x = f2bf(kf.x); w.y = f2bf(kf.y); w.z = f2bf(kf.z); w.w = f2bf(kf.w);
            *(ushort4*)(&kls[kvl * 32 + slot * 8 + (d4 & 1) * 4]) = w;
        }
        // ---- stage V transposed + permuted-k order (bf16 pairs) ----
        // perm within each 32-group: pp = ((kvl>>2)&3)*8 + ((kvl>>4)&1)*4 + (kvl&3)
        // kvl bit-interleave: w&1 -> bit4, so granule-offset bytes spread 4 ways
        #pragma unroll 2
        for (int p = 0; p < 4; ++p) {
            const int m = p * 64 + r0;            // pair index 0..255
            const int grp = m >> 4;
            const int w   = m & 15;
            const int kvl = grp * 32 + ((w & 1) << 4) + ((w >> 1) << 1);  // even
            const float* vp = Vg + (size_t)kvl * DM + d4 * 4;
            const float4 a = *(const float4*)vp;
            const float4 b = *(const float4*)(vp + DM);
            const float av[4] = {a.x, a.y, a.z, a.w};
            const float bv[4] = {b.x, b.y, b.z, b.w};
            const int pp  = ((kvl >> 2) & 3) * 8 + ((kvl >> 4) & 1) * 4 + (kvl & 3);
            const int idx = (kvl & ~31) + pp;     // permuted index in row, even
            const int g  = idx >> 3;
            const int go = idx & 7;
            #pragma unroll
            for (int i = 0; i < 4; ++i) {
                const int d = d4 * 4 + i;
                const unsigned int pk =
                    (unsigned int)f2bf(av[i]) | ((unsigned int)f2bf(bv[i]) << 16);
                *(unsigned int*)(&vtls[d * CHUNK + (g ^ fxor(d)) * 8 + go]) = pk;
            }
        }
    }
    __syncthreads();

    #pragma unroll 1
    for (int ii = 0; ii < 16; ++ii) {
        // WAVE PHASE STAGGER: wave w starts at tile (w*2)&15 and wraps.
        const int it = (ii + wave * 2) & 15;
        const int c0 = it * 32;   // kv base

        // K A-fragments (rows k, depth d)
        const bf16x8 kb0 = *(const bf16x8*)(&kls[(c0 + lr) * 32 + kslot]);
        const bf16x8 kb1 = *(const bf16x8*)(&kls[(c0 + 16 + lr) * 32 + kslot]);
        // V B-fragments: permuted layout -> single b128 each (rows lr, 16+lr)
        const int G = it * 4 + lh;
        const bf16x8 vb0 = *(const bf16x8*)(&vtls[lr * CHUNK + (G ^ fxor(lr)) * 8]);
        const bf16x8 vb1 = *(const bf16x8*)(&vtls[(16 + lr) * CHUNK + (G ^ fxor(16 + lr)) * 8]);

        // process q-tiles in groups of 2: 4 batched QK MFMAs, then softmax+PV
        #pragma unroll
        for (int gq = 0; gq < 2; ++gq) {
            f32x4 s0[2], s1[2];
            #pragma unroll
            for (int u = 0; u < 2; ++u) {
                const int t = gq * 2 + u;
                s0[u] = __builtin_amdgcn_mfma_f32_16x16x32_bf16(kb0, qf[t], minit, 0, 0, 0);
                s1[u] = __builtin_amdgcn_mfma_f32_16x16x32_bf16(kb1, qf[t], minit, 0, 0, 0);
            }
            #pragma unroll
            for (int u = 0; u < 2; ++u) {
                const int t = gq * 2 + u;
                float p0[4], p1[4];
                #pragma unroll
                for (int r = 0; r < 4; ++r) {
                    p0[r] = FEXP2(s0[u][r]);
                    p1[r] = FEXP2(s1[u][r]);
                }
                ls[t] += (p0[0] + p0[1] + p0[2] + p0[3]) +
                         (p1[0] + p1[1] + p1[2] + p1[3]);

                union { unsigned int w[4]; bf16x8 v; } pa;
                pa.w[0] = pack_bf16_trunc(p0[0], p0[1]);
                pa.w[1] = pack_bf16_trunc(p0[2], p0[3]);
                pa.w[2] = pack_bf16_trunc(p1[0], p1[1]);
                pa.w[3] = pack_bf16_trunc(p1[2], p1[3]);

                o0[t] = __builtin_amdgcn_mfma_f32_16x16x32_bf16(pa.v, vb0, o0[t], 0, 0, 0);
                o1[t] = __builtin_amdgcn_mfma_f32_16x16x32_bf16(pa.v, vb1, o1[t], 0, 0, 0);
            }
        }
    }

    // ------- epilogue: reduce row-sums (q = lr lane-local), normalize, store ----
    #pragma unroll
    for (int t = 0; t < 4; ++t) {
        float s = ls[t];
        s += __shfl_xor(s, 16);
        s += __shfl_xor(s, 32);   // all lanes now hold total for q = lr
        #pragma unroll
        for (int r = 0; r < 4; ++r) {
            const float inv = 1.0f / __shfl(s, lh * 4 + r);
            float* orow = Og + (size_t)(wave * 64 + t * 16 + lh * 4 + r) * DM;
            orow[lr]      = o0[t][r] * inv;
            orow[16 + lr] = o1[t][r] * inv;
        }
    }
}

extern "C" void kernel_launch(void* const* d_in, const int* in_sizes, int n_in,
                              void* d_out, int out_size, void* d_ws, size_t ws_size,
                              hipStream_t stream) {
    const float* Q = (const float*)d_in[0];
    const float* K = (const float*)d_in[1];
    const float* V = (const float*)d_in[2];
    float* O = (float*)d_out;
    attn_mha_kernel<<<dim3(96 * 8), dim3(512), 0, stream>>>(Q, K, V, O);
}

// Round 18
// 51.396 us; speedup vs baseline: 1.2229x; 1.0410x over previous
//
#include <hip/hip_runtime.h>
#include <hip/hip_bf16.h>

// AttentionLayer: B=8, T=12, N=512, D=256, H=8, head_dim=32, fp32 in/out.
// 768 blocks (one per bt,h) x 512 threads (8 waves), launch_bounds (512,4).
// Single 512-kv stage (64 KB LDS; 2 blocks/CU). Swapped QK^T: s = mfma(K,Q,-12)
// -> P lane-local (C rows = q), exp2 feeds PV A-operand directly.
// R18 (VALU-trim bundle; base = R12, stagger dropped as neutral):
//  1) pa pack via v_perm_b32 (1 op/word vs 2),
//  2) row-sum via ones-MFMA into lsa (VALU adds -> MFMA pipe; epilogue
//     shuffle-free: lsa[t][r] IS the denominator for the row o0[t][r] stores),
//  3) V-staging pack via v_perm (truncation; error ~2^-8 rel, margin 4x).
// Ledger: cap85 spills (R3,R8); cap128 clean 53.4us (R12); unroll-8 spills
// (R9); q-split staging-dominated (R11); setprio hurts (R14); kb-prefetch
// neutral (R15); 8-wave/64-reg occupancy no-win (R16); stagger neutral (R17).

#define N_    512
#define DM    256
#define DH    32
#define CHUNK 512

typedef __attribute__((ext_vector_type(8))) short bf16x8;
typedef __attribute__((ext_vector_type(4))) float f32x4;

#if defined(__has_builtin)
#  if __has_builtin(__builtin_amdgcn_exp2f)
#    define FEXP2(x) __builtin_amdgcn_exp2f(x)
#  endif
#endif
#ifndef FEXP2
#  define FEXP2(x) exp2f(x)
#endif

__device__ __forceinline__ unsigned short f2bf(float f) {
    unsigned int u = __builtin_bit_cast(unsigned int, f);
    return (unsigned short)((u + 0x8000u) >> 16);   // round-half-up
}

__device__ __forceinline__ unsigned int pack_hi16(float a, float b) {
    // result = { b[31:16], a[31:16] } : truncation-pack in ONE v_perm_b32.
    // pool: idx0-3 = 2nd arg bytes, idx4-7 = 1st arg bytes; sel 0x07060302
    // picks b3,b2 (hi16 of b) then a3,a2 (hi16 of a).
    return __builtin_amdgcn_perm(__builtin_bit_cast(unsigned int, b),
                                 __builtin_bit_cast(unsigned int, a),
                                 0x07060302u);
}

__device__ __forceinline__ int fxor(int d) {
    // V granule swizzle: varies with d>>2 (per-lane) and d&3 (per-unroll-step)
    return ((d >> 2) ^ ((d & 3) << 1)) & 7;
}

__global__ __launch_bounds__(512, 4) void attn_mha_kernel(
    const float* __restrict__ Q, const float* __restrict__ K,
    const float* __restrict__ V, float* __restrict__ O)
{
    // 32 KB (K) + 32 KB (V, permuted) = 65536 B LDS; 2 blocks/CU (wave-limited)
    __shared__ unsigned short kls[CHUNK * DH];   // K[kvl][d], granule slot = (d4>>1)^((kvl>>1)&3)
    __shared__ unsigned short vtls[DH * CHUNK];  // VT[d][perm(kvl)], granule ^= fxor(d)

    const int tid = threadIdx.x;
    const int bt = blockIdx.x >> 3;
    const int h  = blockIdx.x & 7;
    const size_t base = (size_t)bt * (N_ * DM) + (size_t)h * DH;
    const float* Qg = Q + base;
    const float* Kg = K + base;
    const float* Vg = V + base;
    float*       Og = O + base;

    const int wave = tid >> 6;
    const int lane = tid & 63;
    const int lr = lane & 15;   // q col for QK; A-row q / B-col d for PV
    const int lh = lane >> 4;   // depth group 0..3

    const float QSC = 0.25500826170f;             // log2(e)/sqrt(32)
    const int kslot = (lh ^ ((lr >> 1) & 3)) * 8; // K-frag swizzled granule (u16 units)

    // ---------------- Q fragments: 4 tiles of 16 rows per wave ----------------
    bf16x8 qf[4];
    #pragma unroll
    for (int t = 0; t < 4; ++t) {
        const int q0 = wave * 64 + t * 16;
        const float* qp = Qg + (size_t)(q0 + lr) * DM + lh * 8;
        const float4 qa = *(const float4*)qp;
        const float4 qb = *(const float4*)(qp + 4);
        bf16x8 q;
        q[0] = (short)f2bf(qa.x * QSC); q[1] = (short)f2bf(qa.y * QSC);
        q[2] = (short)f2bf(qa.z * QSC); q[3] = (short)f2bf(qa.w * QSC);
        q[4] = (short)f2bf(qb.x * QSC); q[5] = (short)f2bf(qb.y * QSC);
        q[6] = (short)f2bf(qb.z * QSC); q[7] = (short)f2bf(qb.w * QSC);
        qf[t] = q;
    }

    // ones B-fragment for the row-sum MFMA (bf16 1.0 = 0x3F80)
    bf16x8 ones;
    #pragma unroll
    for (int i = 0; i < 8; ++i) ones[i] = (short)0x3F80;

    f32x4 o0[4], o1[4], lsa[4];
    #pragma unroll
    for (int t = 0; t < 4; ++t) {
        o0[t]  = (f32x4){0.f, 0.f, 0.f, 0.f};
        o1[t]  = (f32x4){0.f, 0.f, 0.f, 0.f};
        lsa[t] = (f32x4){0.f, 0.f, 0.f, 0.f};
    }

    // s = (q.k)*log2(e)/sqrt(d) - 12 directly via MFMA C-init.
    const f32x4 minit = {-12.f, -12.f, -12.f, -12.f};

    // ---------------- stage K (bf16), all 512 kv ----------------
    {
        const int d4 = tid & 7;    // d = 4*d4
        const int r0 = tid >> 3;   // 0..63
        #pragma unroll 2
        for (int p = 0; p < 8; ++p) {
            const int kvl = p * 64 + r0;          // 0..511
            const float4 kf = *(const float4*)(Kg + (size_t)kvl * DM + d4 * 4);
            const int slot = (d4 >> 1) ^ ((kvl >> 1) & 3);
            ushort4 w;
            w.x = f2bf(kf.x); w.y = f2bf(kf.y); w.z = f2bf(kf.z); w.w = f2bf(kf.w);
            *(ushort4*)(&kls[kvl * 32 + slot * 8 + (d4 & 1) * 4]) = w;
        }
        // ---- stage V transposed + permuted-k order (bf16 pairs, v_perm pack) ----
        // perm within each 32-group: pp = ((kvl>>2)&3)*8 + ((kvl>>4)&1)*4 + (kvl&3)
        // kvl bit-interleave: w&1 -> bit4, so granule-offset bytes spread 4 ways
        #pragma unroll 2
        for (int p = 0; p < 4; ++p) {
            const int m = p * 64 + r0;            // pair index 0..255
            const int grp = m >> 4;
            const int w   = m & 15;
            const int kvl = grp * 32 + ((w & 1) << 4) + ((w >> 1) << 1);  // even
            const float* vp = Vg + (size_t)kvl * DM + d4 * 4;
            const float4 a = *(const float4*)vp;
            const float4 b = *(const float4*)(vp + DM);
            const float av[4] = {a.x, a.y, a.z, a.w};
            const float bv[4] = {b.x, b.y, b.z, b.w};
            const int pp  = ((kvl >> 2) & 3) * 8 + ((kvl >> 4) & 1) * 4 + (kvl & 3);
            const int idx = (kvl & ~31) + pp;     // permuted index in row, even
            const int g  = idx >> 3;
            const int go = idx & 7;
            #pragma unroll
            for (int i = 0; i < 4; ++i) {
                const int d = d4 * 4 + i;
                const unsigned int pk = pack_hi16(av[i], bv[i]);  // lo=bf16t(av), hi=bf16t(bv)
                *(unsigned int*)(&vtls[d * CHUNK + (g ^ fxor(d)) * 8 + go]) = pk;
            }
        }
    }
    __syncthreads();

    #pragma unroll 1
    for (int it = 0; it < 16; ++it) {
        const int c0 = it * 32;   // kv base

        // K A-fragments (rows k, depth d)
        const bf16x8 kb0 = *(const bf16x8*)(&kls[(c0 + lr) * 32 + kslot]);
        const bf16x8 kb1 = *(const bf16x8*)(&kls[(c0 + 16 + lr) * 32 + kslot]);
        // V B-fragments: permuted layout -> single b128 each (rows lr, 16+lr)
        const int G = it * 4 + lh;
        const bf16x8 vb0 = *(const bf16x8*)(&vtls[lr * CHUNK + (G ^ fxor(lr)) * 8]);
        const bf16x8 vb1 = *(const bf16x8*)(&vtls[(16 + lr) * CHUNK + (G ^ fxor(16 + lr)) * 8]);

        // process q-tiles in groups of 2: 4 batched QK MFMAs, then softmax+PV
        #pragma unroll
        for (int gq = 0; gq < 2; ++gq) {
            f32x4 s0[2], s1[2];
            #pragma unroll
            for (int u = 0; u < 2; ++u) {
                const int t = gq * 2 + u;
                s0[u] = __builtin_amdgcn_mfma_f32_16x16x32_bf16(kb0, qf[t], minit, 0, 0, 0);
                s1[u] = __builtin_amdgcn_mfma_f32_16x16x32_bf16(kb1, qf[t], minit, 0, 0, 0);
            }
            #pragma unroll
            for (int u = 0; u < 2; ++u) {
                const int t = gq * 2 + u;
                float p0[4], p1[4];
                #pragma unroll
                for (int r = 0; r < 4; ++r) {
                    p0[r] = FEXP2(s0[u][r]);
                    p1[r] = FEXP2(s1[u][r]);
                }
                union { unsigned int w[4]; bf16x8 v; } pa;
                pa.w[0] = pack_hi16(p0[0], p0[1]);
                pa.w[1] = pack_hi16(p0[2], p0[3]);
                pa.w[2] = pack_hi16(p1[0], p1[1]);
                pa.w[3] = pack_hi16(p1[2], p1[3]);

                lsa[t] = __builtin_amdgcn_mfma_f32_16x16x32_bf16(pa.v, ones, lsa[t], 0, 0, 0);
                o0[t]  = __builtin_amdgcn_mfma_f32_16x16x32_bf16(pa.v, vb0, o0[t], 0, 0, 0);
                o1[t]  = __builtin_amdgcn_mfma_f32_16x16x32_bf16(pa.v, vb1, o1[t], 0, 0, 0);
            }
        }
    }

    // ---- epilogue: shuffle-free — lsa[t][r] is the rowsum for the q-row that
    // ---- o0[t][r]/o1[t][r] belong to (D rows = q in the swapped structure).
    #pragma unroll
    for (int t = 0; t < 4; ++t) {
        #pragma unroll
        for (int r = 0; r < 4; ++r) {
            const float inv = 1.0f / lsa[t][r];
            float* orow = Og + (size_t)(wave * 64 + t * 16 + lh * 4 + r) * DM;
            orow[lr]      = o0[t][r] * inv;
            orow[16 + lr] = o1[t][r] * inv;
        }
    }
}

extern "C" void kernel_launch(void* const* d_in, const int* in_sizes, int n_in,
                              void* d_out, int out_size, void* d_ws, size_t ws_size,
                              hipStream_t stream) {
    const float* Q = (const float*)d_in[0];
    const float* K = (const float*)d_in[1];
    const float* V = (const float*)d_in[2];
    float* O = (float*)d_out;
    attn_mha_kernel<<<dim3(96 * 8), dim3(512), 0, stream>>>(Q, K, V, O);
}

// Round 19
// 50.408 us; speedup vs baseline: 1.2468x; 1.0196x over previous
//
#include <hip/hip_runtime.h>
#include <hip/hip_bf16.h>

// AttentionLayer: B=8, T=12, N=512, D=256, H=8, head_dim=32, fp32 in/out.
// 768 blocks (one per bt,h) x 512 threads (8 waves), launch_bounds (512,4).
// Single 512-kv stage (64 KB LDS; 2 blocks/CU). Swapped QK^T: s = mfma(K,Q,-12)
// -> P lane-local (C rows = q), exp2 feeds PV A-operand directly.
// R18 (VALU-trim bundle; base = R12, stagger dropped as neutral):
//  1) pa pack via v_perm_b32 (1 op/word vs 2),
//  2) row-sum via ones-MFMA into lsa (VALU adds -> MFMA pipe; epilogue
//     shuffle-free: lsa[t][r] IS the denominator for the row o0[t][r] stores),
//  3) V-staging pack via v_perm (truncation; error ~2^-8 rel, margin 4x).
// Ledger: cap85 spills (R3,R8); cap128 clean 53.4us (R12); unroll-8 spills
// (R9); q-split staging-dominated (R11); setprio hurts (R14); kb-prefetch
// neutral (R15); 8-wave/64-reg occupancy no-win (R16); stagger neutral (R17).

#define N_    512
#define DM    256
#define DH    32
#define CHUNK 512

typedef __attribute__((ext_vector_type(8))) short bf16x8;
typedef __attribute__((ext_vector_type(4))) float f32x4;

#if defined(__has_builtin)
#  if __has_builtin(__builtin_amdgcn_exp2f)
#    define FEXP2(x) __builtin_amdgcn_exp2f(x)
#  endif
#endif
#ifndef FEXP2
#  define FEXP2(x) exp2f(x)
#endif

__device__ __forceinline__ unsigned short f2bf(float f) {
    unsigned int u = __builtin_bit_cast(unsigned int, f);
    return (unsigned short)((u + 0x8000u) >> 16);   // round-half-up
}

__device__ __forceinline__ unsigned int pack_hi16(float a, float b) {
    // result = { b[31:16], a[31:16] } : truncation-pack in ONE v_perm_b32.
    // pool: idx0-3 = 2nd arg bytes, idx4-7 = 1st arg bytes; sel 0x07060302
    // picks b3,b2 (hi16 of b) then a3,a2 (hi16 of a).
    return __builtin_amdgcn_perm(__builtin_bit_cast(unsigned int, b),
                                 __builtin_bit_cast(unsigned int, a),
                                 0x07060302u);
}

__device__ __forceinline__ int fxor(int d) {
    // V granule swizzle: varies with d>>2 (per-lane) and d&3 (per-unroll-step)
    return ((d >> 2) ^ ((d & 3) << 1)) & 7;
}

__global__ __launch_bounds__(512, 4) void attn_mha_kernel(
    const float* __restrict__ Q, const float* __restrict__ K,
    const float* __restrict__ V, float* __restrict__ O)
{
    // 32 KB (K) + 32 KB (V, permuted) = 65536 B LDS; 2 blocks/CU (wave-limited)
    __shared__ unsigned short kls[CHUNK * DH];   // K[kvl][d], granule slot = (d4>>1)^((kvl>>1)&3)
    __shared__ unsigned short vtls[DH * CHUNK];  // VT[d][perm(kvl)], granule ^= fxor(d)

    const int tid = threadIdx.x;
    const int bt = blockIdx.x >> 3;
    const int h  = blockIdx.x & 7;
    const size_t base = (size_t)bt * (N_ * DM) + (size_t)h * DH;
    const float* Qg = Q + base;
    const float* Kg = K + base;
    const float* Vg = V + base;
    float*       Og = O + base;

    const int wave = tid >> 6;
    const int lane = tid & 63;
    const int lr = lane & 15;   // q col for QK; A-row q / B-col d for PV
    const int lh = lane >> 4;   // depth group 0..3

    const float QSC = 0.25500826170f;             // log2(e)/sqrt(32)
    const int kslot = (lh ^ ((lr >> 1) & 3)) * 8; // K-frag swizzled granule (u16 units)

    // ---------------- Q fragments: 4 tiles of 16 rows per wave ----------------
    bf16x8 qf[4];
    #pragma unroll
    for (int t = 0; t < 4; ++t) {
        const int q0 = wave * 64 + t * 16;
        const float* qp = Qg + (size_t)(q0 + lr) * DM + lh * 8;
        const float4 qa = *(const float4*)qp;
        const float4 qb = *(const float4*)(qp + 4);
        bf16x8 q;
        q[0] = (short)f2bf(qa.x * QSC); q[1] = (short)f2bf(qa.y * QSC);
        q[2] = (short)f2bf(qa.z * QSC); q[3] = (short)f2bf(qa.w * QSC);
        q[4] = (short)f2bf(qb.x * QSC); q[5] = (short)f2bf(qb.y * QSC);
        q[6] = (short)f2bf(qb.z * QSC); q[7] = (short)f2bf(qb.w * QSC);
        qf[t] = q;
    }

    // ones B-fragment for the row-sum MFMA (bf16 1.0 = 0x3F80)
    bf16x8 ones;
    #pragma unroll
    for (int i = 0; i < 8; ++i) ones[i] = (short)0x3F80;

    f32x4 o0[4], o1[4], lsa[4];
    #pragma unroll
    for (int t = 0; t < 4; ++t) {
        o0[t]  = (f32x4){0.f, 0.f, 0.f, 0.f};
        o1[t]  = (f32x4){0.f, 0.f, 0.f, 0.f};
        lsa[t] = (f32x4){0.f, 0.f, 0.f, 0.f};
    }

    // s = (q.k)*log2(e)/sqrt(d) - 12 directly via MFMA C-init.
    const f32x4 minit = {-12.f, -12.f, -12.f, -12.f};

    // ---------------- stage K (bf16), all 512 kv ----------------
    {
        const int d4 = tid & 7;    // d = 4*d4
        const int r0 = tid >> 3;   // 0..63
        #pragma unroll 2
        for (int p = 0; p < 8; ++p) {
            const int kvl = p * 64 + r0;          // 0..511
            const float4 kf = *(const float4*)(Kg + (size_t)kvl * DM + d4 * 4);
            const int slot = (d4 >> 1) ^ ((kvl >> 1) & 3);
            ushort4 w;
            w.x = f2bf(kf.x); w.y = f2bf(kf.y); w.z = f2bf(kf.z); w.w = f2bf(kf.w);
            *(ushort4*)(&kls[kvl * 32 + slot * 8 + (d4 & 1) * 4]) = w;
        }
        // ---- stage V transposed + permuted-k order (bf16 pairs, v_perm pack) ----
        // perm within each 32-group: pp = ((kvl>>2)&3)*8 + ((kvl>>4)&1)*4 + (kvl&3)
        // kvl bit-interleave: w&1 -> bit4, so granule-offset bytes spread 4 ways
        #pragma unroll 2
        for (int p = 0; p < 4; ++p) {
            const int m = p * 64 + r0;            // pair index 0..255
            const int grp = m >> 4;
            const int w   = m & 15;
            const int kvl = grp * 32 + ((w & 1) << 4) + ((w >> 1) << 1);  // even
            const float* vp = Vg + (size_t)kvl * DM + d4 * 4;
            const float4 a = *(const float4*)vp;
            const float4 b = *(const float4*)(vp + DM);
            const float av[4] = {a.x, a.y, a.z, a.w};
            const float bv[4] = {b.x, b.y, b.z, b.w};
            const int pp  = ((kvl >> 2) & 3) * 8 + ((kvl >> 4) & 1) * 4 + (kvl & 3);
            const int idx = (kvl & ~31) + pp;     // permuted index in row, even
            const int g  = idx >> 3;
            const int go = idx & 7;
            #pragma unroll
            for (int i = 0; i < 4; ++i) {
                const int d = d4 * 4 + i;
                const unsigned int pk = pack_hi16(av[i], bv[i]);  // lo=bf16t(av), hi=bf16t(bv)
                *(unsigned int*)(&vtls[d * CHUNK + (g ^ fxor(d)) * 8 + go]) = pk;
            }
        }
    }
    __syncthreads();

    #pragma unroll 1
    for (int it = 0; it < 16; ++it) {
        const int c0 = it * 32;   // kv base

        // K A-fragments (rows k, depth d)
        const bf16x8 kb0 = *(const bf16x8*)(&kls[(c0 + lr) * 32 + kslot]);
        const bf16x8 kb1 = *(const bf16x8*)(&kls[(c0 + 16 + lr) * 32 + kslot]);
        // V B-fragments: permuted layout -> single b128 each (rows lr, 16+lr)
        const int G = it * 4 + lh;
        const bf16x8 vb0 = *(const bf16x8*)(&vtls[lr * CHUNK + (G ^ fxor(lr)) * 8]);
        const bf16x8 vb1 = *(const bf16x8*)(&vtls[(16 + lr) * CHUNK + (G ^ fxor(16 + lr)) * 8]);

        // process q-tiles in groups of 2: 4 batched QK MFMAs, then softmax+PV
        #pragma unroll
        for (int gq = 0; gq < 2; ++gq) {
            f32x4 s0[2], s1[2];
            #pragma unroll
            for (int u = 0; u < 2; ++u) {
                const int t = gq * 2 + u;
                s0[u] = __builtin_amdgcn_mfma_f32_16x16x32_bf16(kb0, qf[t], minit, 0, 0, 0);
                s1[u] = __builtin_amdgcn_mfma_f32_16x16x32_bf16(kb1, qf[t], minit, 0, 0, 0);
            }
            #pragma unroll
            for (int u = 0; u < 2; ++u) {
                const int t = gq * 2 + u;
                float p0[4], p1[4];
                #pragma unroll
                for (int r = 0; r < 4; ++r) {
                    p0[r] = FEXP2(s0[u][r]);
                    p1[r] = FEXP2(s1[u][r]);
                }
                union { unsigned int w[4]; bf16x8 v; } pa;
                pa.w[0] = pack_hi16(p0[0], p0[1]);
                pa.w[1] = pack_hi16(p0[2], p0[3]);
                pa.w[2] = pack_hi16(p1[0], p1[1]);
                pa.w[3] = pack_hi16(p1[2], p1[3]);

                lsa[t] = __builtin_amdgcn_mfma_f32_16x16x32_bf16(pa.v, ones, lsa[t], 0, 0, 0);
                o0[t]  = __builtin_amdgcn_mfma_f32_16x16x32_bf16(pa.v, vb0, o0[t], 0, 0, 0);
                o1[t]  = __builtin_amdgcn_mfma_f32_16x16x32_bf16(pa.v, vb1, o1[t], 0, 0, 0);
            }
        }
    }

    // ---- epilogue: shuffle-free — lsa[t][r] is the rowsum for the q-row that
    // ---- o0[t][r]/o1[t][r] belong to (D rows = q in the swapped structure).
    #pragma unroll
    for (int t = 0; t < 4; ++t) {
        #pragma unroll
        for (int r = 0; r < 4; ++r) {
            const float inv = 1.0f / lsa[t][r];
            float* orow = Og + (size_t)(wave * 64 + t * 16 + lh * 4 + r) * DM;
            orow[lr]      = o0[t][r] * inv;
            orow[16 + lr] = o1[t][r] * inv;
        }
    }
}

extern "C" void kernel_launch(void* const* d_in, const int* in_sizes, int n_in,
                              void* d_out, int out_size, void* d_ws, size_t ws_size,
                              hipStream_t stream) {
    const float* Q = (const float*)d_in[0];
    const float* K = (const float*)d_in[1];
    const float* V = (const float*)d_in[2];
    float* O = (float*)d_out;
    attn_mha_kernel<<<dim3(96 * 8), dim3(512), 0, stream>>>(Q, K, V, O);
}